// Round 1
// baseline (119.315 us; speedup 1.0000x reference)
//
#include <hip/hip_runtime.h>
#include <math.h>

#define WIN  11
#define PAD  5
#define TILE 32
#define REG  42   // TILE + WIN - 1
#define IMG  512
#define NB   32

struct GaussW { float w[WIN]; };

__global__ __launch_bounds__(256) void ssim_main(
    const float* __restrict__ img1, const float* __restrict__ img2,
    float* __restrict__ partial, GaussW gw)
{
    __shared__ float g1[REG][REG];
    __shared__ float g2[REG][REG];
    __shared__ float H[5][REG][TILE];

    const int bx = blockIdx.x, by = blockIdx.y, n = blockIdx.z;
    const int tid = threadIdx.x;
    const int x0 = bx * TILE - PAD;
    const int y0 = by * TILE - PAD;

    const float* b1 = img1 + (size_t)n * 3 * IMG * IMG;
    const float* b2 = img2 + (size_t)n * 3 * IMG * IMG;

    // Stage gray halo region (reflect padding) for both images
    for (int i = tid; i < REG * REG; i += 256) {
        int r = i / REG, c = i % REG;
        int gy = y0 + r; gy = gy < 0 ? -gy : (gy > IMG - 1 ? 2 * (IMG - 1) - gy : gy);
        int gx = x0 + c; gx = gx < 0 ? -gx : (gx > IMG - 1 ? 2 * (IMG - 1) - gx : gx);
        int idx = gy * IMG + gx;
        float r1 = b1[idx], e1 = b1[IMG * IMG + idx], c1 = b1[2 * IMG * IMG + idx];
        float r2 = b2[idx], e2 = b2[IMG * IMG + idx], c2 = b2[2 * IMG * IMG + idx];
        g1[r][c] = 0.299f * r1 + 0.587f * e1 + 0.114f * c1;
        g2[r][c] = 0.299f * r2 + 0.587f * e2 + 0.114f * c2;
    }
    __syncthreads();

    // Horizontal separable pass: 5 filtered quantities
    for (int i = tid; i < REG * TILE; i += 256) {
        int r = i / TILE, c = i % TILE;
        float s0 = 0.f, s1 = 0.f, s2 = 0.f, s3 = 0.f, s4 = 0.f;
        #pragma unroll
        for (int t = 0; t < WIN; ++t) {
            float a = g1[r][c + t];
            float b = g2[r][c + t];
            float w = gw.w[t];
            s0 = fmaf(w, a, s0);
            s1 = fmaf(w, b, s1);
            s2 = fmaf(w, a * a, s2);
            s3 = fmaf(w, b * b, s3);
            s4 = fmaf(w, a * b, s4);
        }
        H[0][r][c] = s0; H[1][r][c] = s1; H[2][r][c] = s2;
        H[3][r][c] = s3; H[4][r][c] = s4;
    }
    __syncthreads();

    // Vertical pass + SSIM + interior-masked accumulation
    const float C1 = 1e-4f, C2 = 9e-4f;
    const float COVN = 121.0f / 120.0f;
    float lsum = 0.0f;
    for (int i = tid; i < TILE * TILE; i += 256) {
        int r = i / TILE, c = i % TILE;
        int oy = by * TILE + r, ox = bx * TILE + c;
        float ux = 0.f, uy = 0.f, uxx = 0.f, uyy = 0.f, uxy = 0.f;
        #pragma unroll
        for (int t = 0; t < WIN; ++t) {
            float w = gw.w[t];
            ux  = fmaf(w, H[0][r + t][c], ux);
            uy  = fmaf(w, H[1][r + t][c], uy);
            uxx = fmaf(w, H[2][r + t][c], uxx);
            uyy = fmaf(w, H[3][r + t][c], uyy);
            uxy = fmaf(w, H[4][r + t][c], uxy);
        }
        if (oy >= PAD && oy < IMG - PAD && ox >= PAD && ox < IMG - PAD) {
            float vx  = COVN * (uxx - ux * ux);
            float vy  = COVN * (uyy - uy * uy);
            float vxy = COVN * (uxy - ux * uy);
            float A1 = 2.0f * ux * uy + C1;
            float A2 = 2.0f * vxy + C2;
            float B1 = ux * ux + uy * uy + C1;
            float B2 = vx + vy + C2;
            lsum += (A1 * A2) / (B1 * B2);
        }
    }

    // Block reduction: wave shuffle then LDS
    for (int off = 32; off > 0; off >>= 1)
        lsum += __shfl_down(lsum, off, 64);
    __shared__ float wsum[4];
    const int wid = tid >> 6, lane = tid & 63;
    if (lane == 0) wsum[wid] = lsum;
    __syncthreads();
    if (tid == 0) {
        partial[((size_t)n * gridDim.y + by) * gridDim.x + bx] =
            wsum[0] + wsum[1] + wsum[2] + wsum[3];
    }
}

__global__ __launch_bounds__(256) void ssim_reduce(
    const float* __restrict__ partial, float* __restrict__ out,
    int nblocks, double inv_count)
{
    __shared__ double sm[256];
    double s = 0.0;
    for (int i = threadIdx.x; i < nblocks; i += 256) s += (double)partial[i];
    sm[threadIdx.x] = s;
    __syncthreads();
    for (int off = 128; off > 0; off >>= 1) {
        if (threadIdx.x < off) sm[threadIdx.x] += sm[threadIdx.x + off];
        __syncthreads();
    }
    if (threadIdx.x == 0) out[0] = (float)(sm[0] * inv_count);
}

extern "C" void kernel_launch(void* const* d_in, const int* in_sizes, int n_in,
                              void* d_out, int out_size, void* d_ws, size_t ws_size,
                              hipStream_t stream) {
    const float* img1 = (const float*)d_in[0];
    const float* img2 = (const float*)d_in[1];
    float* out = (float*)d_out;
    float* partial = (float*)d_ws;

    // Host-side Gaussian 1D weights (sigma = 1.5, radius 5, normalized)
    GaussW gw;
    {
        double e[WIN], s = 0.0;
        for (int i = 0; i < WIN; ++i) {
            double d = (double)(i - PAD);
            e[i] = exp(-(d * d) / (2.0 * 1.5 * 1.5));
            s += e[i];
        }
        for (int i = 0; i < WIN; ++i) gw.w[i] = (float)(e[i] / s);
    }

    const int TX = IMG / TILE, TY = IMG / TILE;          // 16 x 16
    dim3 grid(TX, TY, NB);
    ssim_main<<<grid, 256, 0, stream>>>(img1, img2, partial, gw);

    const int nblocks = TX * TY * NB;                    // 8192
    const double inv_count = 1.0 / (double)((size_t)NB * (IMG - 2 * PAD) * (IMG - 2 * PAD));
    ssim_reduce<<<1, 256, 0, stream>>>(partial, out, nblocks, inv_count);
}